// Round 1
// baseline (146.537 us; speedup 1.0000x reference)
//
#include <hip/hip_runtime.h>
#include <cstdint>
#include <cstddef>

// Problem constants (from reference)
#define B_    2
#define A_    3
#define NCLS_ 3
#define CH_   9      // N_CLS * A
#define D_    64
#define H_    128
#define W_    128
#define M_    128
#define TH    16     // h-rows per tile
#define EPS_      1e-4f
#define ONE_M_EPS 0.9999f
#define NLOG2E    -1.4426950408889634f   // -log2(e)
#define LN2_      0.6931471805599453f

__device__ __forceinline__ float4 fmax4(float4 a, float4 b) {
    return make_float4(fmaxf(a.x, b.x), fmaxf(a.y, b.y),
                       fmaxf(a.z, b.z), fmaxf(a.w, b.w));
}

// gfx950: __builtin_amdgcn_exp2f = v_exp_f32 (2^x), __builtin_amdgcn_logf =
// v_log_f32 (log2 x) — per __clang_hip_math.h.
__device__ __forceinline__ float exp2_fast(float x) { return __builtin_amdgcn_exp2f(x); }
__device__ __forceinline__ float log2_fast(float x) { return __builtin_amdgcn_logf(x); }

// ---------------------------------------------------------------------------
// Negative-term kernel — LDS d-plane sharing (R10).
// R9 analysis: per lane 4 float4 loads/row-iter (center + d-1 + d+1 + pg);
// the d+-1 loads duplicate other half-waves' center loads but the per-CU
// working set (~112 KB across ~4.5 blocks) thrashes the 32 KiB L1, so the 3x
// redundancy is re-served by L2 (~200-400 cyc). Fix: each half-wave loads ONLY
// its own plane row (hw0/hw7 additionally load the d0-1 / d0+8 halo rows),
// stages into a 3-slot rotating LDS buffer, and reads d+-1 rows from LDS.
// Global loads: 32 -> 18 float4 per block-iter (10 logits rows + 8 pg).
// Pipeline: global prefetch stays 2 row-iters deep; loads are issued AFTER
// the per-iter barrier so its implicit vmcnt drain never exposes them.
// Swizzle: 1152 blocks = 8 XCD x 144 chunk (bijective). Tile order within a
// chunk: d-chunk fastest, then cls, then ht -> d-halo neighbors AND the 3
// cls-channels sharing one prob plane sit on the same XCD L2.
// Borders: replicate-clamp for d/h (identity under max); w via lane shuffles
// with -inf select. Exact float max => (pooled == logits) bit-exact.
// ---------------------------------------------------------------------------
__global__ __launch_bounds__(256) void neg_kernel(
    const float* __restrict__ logits, const float* __restrict__ prob,
    float* __restrict__ partials)
{
    const int orig = blockIdx.x;
    const int swz  = (orig & 7) * 144 + (orig >> 3);   // chunked XCD swizzle
    const int hw   = threadIdx.x >> 5;   // 0..7  plane owner within block
    const int lw   = threadIdx.x & 31;   // w-segment index
    const int lane = threadIdx.x & 63;
    const float NEG = -INFINITY;

    // tile decode: dchunk fastest, then cls, then ht, then (b,a)
    const int dchunk = swz & 7;
    int t = swz >> 3;                    // 0..143
    const int cls = t % 3; t /= 3;       // 0..47
    const int ht  = t & 7;
    const int ba  = t >> 3;              // 0..5
    const int b = ba / 3, a = ba % 3;
    const int bc = b * CH_ + cls * A_ + a;   // channel c = cls*A + a
    const int d  = dchunk * 8 + hw;
    const int h0 = ht * TH;

    const size_t HW = (size_t)H_ * W_;
    const float* Ld = logits + ((size_t)bc * D_ + d) * HW + 4 * lw;
    const float* Pb = prob   + (((size_t)b * A_ + a) * D_ + d) * HW + 4 * lw;
    // halo planes: hw0 owns d0-1 (plane 0), hw7 owns d0+8 (plane 9);
    // replicate-clamp at D borders (identity under max)
    const bool hasE = (hw == 0) | (hw == 7);
    const float* Le = (hw == 0) ? ((d > 0) ? Ld - HW : Ld)
                                : ((d + 1 < D_) ? Ld + HW : Ld);
    const int pe = (hw == 0) ? 0 : 9;

    // 3 rotating row-slots x 10 planes x 128 floats = 15 KB
    __shared__ float lds[3][10][128];

    auto ldc = [&](int hh) -> float4 {
        const int hc = min(max(hh, 0), H_ - 1);
        return *(const float4*)(Ld + (size_t)hc * W_);
    };
    auto lde = [&](int hh) -> float4 {
        const int hc = min(max(hh, 0), H_ - 1);
        return *(const float4*)(Le + (size_t)hc * W_);
    };
    auto ldpg = [&](int hh) -> float4 {
        const int hc = min(hh, H_ - 1);
        return *(const float4*)(Pb + (size_t)hc * W_);
    };
    auto ST = [&](int s, float4 c, float4 e) {
        *(float4*)&lds[s][hw + 1][4 * lw] = c;
        if (hasE) *(float4*)&lds[s][pe][4 * lw] = e;
    };
    // 3-plane vertical max: own center row (reg) + d-1/d+1 rows (LDS)
    auto VM = [&](int s, float4 own) -> float4 {
        const float4 x = *(const float4*)&lds[s][hw][4 * lw];
        const float4 y = *(const float4*)&lds[s][hw + 2][4 * lw];
        return fmax4(own, fmax4(x, y));
    };

    // slot indices: row j lives in slot j%3 (conceptual row -1 -> slot 2)
    const int base = h0 % 3;
    const int s_0  = base;
    const int s_p1 = (base + 1 == 3) ? 0 : base + 1;
    const int s_m1 = (base == 0) ? 2 : base - 1;

    // ---- prologue: rows h0-1 .. h0+3 in flight ----
    float4 cA = ldc(h0 - 1);
    float4 cB = ldc(h0), cC = ldc(h0 + 1), cD = ldc(h0 + 2), cE = ldc(h0 + 3);
    float4 eA, eB, eC, eD, eE;
    if (hasE) {
        eA = lde(h0 - 1); eB = lde(h0); eC = lde(h0 + 1);
        eD = lde(h0 + 2); eE = lde(h0 + 3);
    }
    float4 pgB = ldpg(h0), pgC = ldpg(h0 + 1);
    float4 pgD = ldpg(h0 + 2), pgE = ldpg(h0 + 3);

    ST(s_m1, cA, eA);          // row h0-1
    ST(s_0,  cB, eB);          // row h0
    ST(s_p1, cC, eC);          // row h0+1
    __syncthreads();
    float4 vmA = VM(s_m1, cA);
    float4 vmB = VM(s_0,  cB);
    float4 vmC = VM(s_p1, cC);
    __syncthreads();           // protect slot s_m1 before iter-0 overwrite

    float lacc2 = 0.0f, cacc = 0.0f;   // lacc2 accumulates log2 units
    int sW = s_m1;                      // slot of row r+2 at iter i: (h0+2+i)%3

    #pragma unroll
    for (int i = 0; i < TH; ++i) {
        const int r = h0 + i;

        // stage row r+2 (arrived 2 iters ago); last iter's row is unused
        if (i != TH - 1) ST(sW, cD, eD);
        __syncthreads();

        // prefetch row r+4 AFTER the barrier (keeps loads in flight a full
        // 2 row-iters; the barrier's vmcnt drain never touches them)
        float4 cN, eN, pgN;
        if (i <= TH - 4) {
            cN = ldc(r + 4);
            if (hasE) eN = lde(r + 4);
            pgN = ldpg(r + 4);
        }

        // vertical 3-plane max for row r+2
        float4 vmN;
        if (i != TH - 1) vmN = VM(sW, cD);

        // h-direction max for output row r
        float4 cm = fmax4(vmA, fmax4(vmB, vmC));
        // w-direction neighbors across lanes (w tile borders: select)
        const float lftv = __shfl(cm.w, (lane + 63) & 63, 64);
        const float rgtv = __shfl(cm.x, (lane + 1) & 63, 64);
        const float left  = (lw == 0)  ? NEG : lftv;
        const float right = (lw == 31) ? NEG : rgtv;
        float4 m;
        m.x = fmaxf(left, fmaxf(cm.x, cm.y));
        m.y = fmaxf(cm.x, fmaxf(cm.y, cm.z));
        m.z = fmaxf(cm.y, fmaxf(cm.z, cm.w));
        m.w = fmaxf(cm.z, fmaxf(cm.w, right));

        // epilogue: cheap pre-condition; wave-uniform skip of transcendentals
        {
            const float x = cB.x;
            const bool pre = (pgB.x == -1.0f) & (m.x == x);
            if (__any(pre)) {
                const float u = exp2_fast(x * NLOG2E);             // e^-x
                const float p = __builtin_amdgcn_fmed3f(
                                    __builtin_amdgcn_rcpf(1.0f + u), EPS_, ONE_M_EPS);
                const float wn = (pre & (p > EPS_)) ? p * p : 0.0f;
                cacc += wn;
                lacc2 = fmaf(log2_fast(1.0f - p), wn, lacc2);
            }
        }
        {
            const float x = cB.y;
            const bool pre = (pgB.y == -1.0f) & (m.y == x);
            if (__any(pre)) {
                const float u = exp2_fast(x * NLOG2E);
                const float p = __builtin_amdgcn_fmed3f(
                                    __builtin_amdgcn_rcpf(1.0f + u), EPS_, ONE_M_EPS);
                const float wn = (pre & (p > EPS_)) ? p * p : 0.0f;
                cacc += wn;
                lacc2 = fmaf(log2_fast(1.0f - p), wn, lacc2);
            }
        }
        {
            const float x = cB.z;
            const bool pre = (pgB.z == -1.0f) & (m.z == x);
            if (__any(pre)) {
                const float u = exp2_fast(x * NLOG2E);
                const float p = __builtin_amdgcn_fmed3f(
                                    __builtin_amdgcn_rcpf(1.0f + u), EPS_, ONE_M_EPS);
                const float wn = (pre & (p > EPS_)) ? p * p : 0.0f;
                cacc += wn;
                lacc2 = fmaf(log2_fast(1.0f - p), wn, lacc2);
            }
        }
        {
            const float x = cB.w;
            const bool pre = (pgB.w == -1.0f) & (m.w == x);
            if (__any(pre)) {
                const float u = exp2_fast(x * NLOG2E);
                const float p = __builtin_amdgcn_fmed3f(
                                    __builtin_amdgcn_rcpf(1.0f + u), EPS_, ONE_M_EPS);
                const float wn = (pre & (p > EPS_)) ? p * p : 0.0f;
                cacc += wn;
                lacc2 = fmaf(log2_fast(1.0f - p), wn, lacc2);
            }
        }

        // rotate rings
        vmA = vmB; vmB = vmC; vmC = vmN;
        cB = cC; cC = cD; cD = cE; cE = cN;
        if (hasE) { eB = eC; eC = eD; eD = eE; eE = eN; }
        pgB = pgC; pgC = pgD; pgD = pgE; pgE = pgN;
        sW = (sW + 1 == 3) ? 0 : sW + 1;
    }

    float lacc = lacc2 * (-LN2_);      // convert log2 -> -ln

    // block reduction: wave shuffle then cross-wave via LDS
    #pragma unroll
    for (int off = 32; off > 0; off >>= 1) {
        lacc += __shfl_down(lacc, off);
        cacc += __shfl_down(cacc, off);
    }
    __shared__ float rl[4], rc[4];
    const int wv = threadIdx.x >> 6;
    if (lane == 0) { rl[wv] = lacc; rc[wv] = cacc; }
    __syncthreads();
    if (threadIdx.x == 0) {
        partials[2 * (size_t)blockIdx.x]     = rl[0] + rl[1] + rl[2] + rl[3];
        partials[2 * (size_t)blockIdx.x + 1] = rc[0] + rc[1] + rc[2] + rc[3];
    }
}

// ---------------------------------------------------------------------------
// Fused positive/other terms + final reduction (single block).
// Output order: [sum l_pos, loss_neg, sum l_oth, sum c_pos, count_neg, sum c_oth]
// ---------------------------------------------------------------------------
__global__ __launch_bounds__(256) void pos_reduce_kernel(
    const float* __restrict__ logits, const float* __restrict__ prob,
    const int* __restrict__ coord, const float* __restrict__ wcls,
    const float* __restrict__ partials, int nb, float* __restrict__ out)
{
    const int tid = threadIdx.x;
    const int b = tid >> 7;               // 0 or 1
    const int m = tid & (M_ - 1);
    __shared__ int zr[B_][NCLS_];
    if (tid < B_ * NCLS_) zr[tid / NCLS_][tid % NCLS_] = 0;
    __syncthreads();

    const int* cg = coord + ((size_t)b * M_ + m) * 4;
    const int c0 = cg[0];
    const bool valid = c0 > -1;
    const int a = valid ? c0    : 0;
    const int d = valid ? cg[1] : 0;
    const int h = valid ? cg[2] : 0;
    const int w = valid ? cg[3] : 0;

    const size_t HW = (size_t)H_ * W_;
    const size_t sp = (size_t)d * HW + (size_t)h * W_ + w;

    const float pv = prob[((size_t)b * A_ + a) * D_ * HW + sp];
    const int cls = valid ? ((int)pv - 1) : 0;
    if (valid) zr[b][cls] = 1;            // zero_rows flags (benign race)
    __syncthreads();

    auto sigclip = [](float x) {
        float p = 1.0f / (1.0f + __expf(-x));
        return fminf(fmaxf(p, EPS_), ONE_M_EPS);
    };

    const float vf = valid ? 1.0f : 0.0f;
    const float pt = sigclip(logits[((size_t)(b * CH_ + cls * A_ + a)) * D_ * HW + sp]);
    const float wp = (1.0f - pt) * (1.0f - pt) * wcls[cls] * vf;
    float lpos = -__logf(pt) * wp;
    float cpos = wp;

    float loth = 0.0f, coth = 0.0f;
    const bool ptg = pt > 0.5f;
    #pragma unroll
    for (int cc = 0; cc < NCLS_; ++cc) {
        const float po = sigclip(logits[((size_t)(b * CH_ + cc * A_ + a)) * D_ * HW + sp]);
        float wo = fmaxf(po - (pt - 0.1f), 0.0f);
        wo = (po > 0.5f && ptg) ? wo : 0.0f;
        wo = zr[b][cc] ? 0.0f : wo;
        wo *= vf;
        loth -= __logf(1.0f - po) * wo;
        coth += wo;
    }

    // neg partials (grid is 1 block; stride over nb)
    float l = 0.0f, c = 0.0f;
    for (int i = tid; i < nb; i += 256) {
        l += partials[2 * (size_t)i];
        c += partials[2 * (size_t)i + 1];
    }

    #pragma unroll
    for (int off = 32; off > 0; off >>= 1) {
        lpos += __shfl_down(lpos, off);
        cpos += __shfl_down(cpos, off);
        loth += __shfl_down(loth, off);
        coth += __shfl_down(coth, off);
        l    += __shfl_down(l, off);
        c    += __shfl_down(c, off);
    }
    __shared__ float r6[4][6];
    const int lane = tid & 63, wv = tid >> 6;
    if (lane == 0) {
        r6[wv][0] = lpos; r6[wv][1] = cpos; r6[wv][2] = loth;
        r6[wv][3] = coth; r6[wv][4] = l;    r6[wv][5] = c;
    }
    __syncthreads();
    if (tid == 0) {
        out[0] = r6[0][0] + r6[1][0] + r6[2][0] + r6[3][0];  // sum l_pos
        out[3] = r6[0][1] + r6[1][1] + r6[2][1] + r6[3][1];  // sum c_pos
        out[2] = r6[0][2] + r6[1][2] + r6[2][2] + r6[3][2];  // sum l_oth
        out[5] = r6[0][3] + r6[1][3] + r6[2][3] + r6[3][3];  // sum c_oth
        out[1] = r6[0][4] + r6[1][4] + r6[2][4] + r6[3][4];  // loss_neg
        out[4] = r6[0][5] + r6[1][5] + r6[2][5] + r6[3][5];  // count_neg
    }
}

extern "C" void kernel_launch(void* const* d_in, const int* in_sizes, int n_in,
                              void* d_out, int out_size, void* d_ws, size_t ws_size,
                              hipStream_t stream)
{
    const float* logits = (const float*)d_in[0];
    const float* prob   = (const float*)d_in[1];
    const int*   coord  = (const int*)d_in[2];
    const float* wcls   = (const float*)d_in[3];
    float* out = (float*)d_out;

    const int nb = B_ * CH_ * (D_ / 8) * (H_ / TH);    // 1152 blocks, exact

    float* partials = (float*)d_ws;          // nb * 2 floats

    neg_kernel<<<dim3(nb), dim3(256), 0, stream>>>(logits, prob, partials);
    pos_reduce_kernel<<<dim3(1), dim3(256), 0, stream>>>(logits, prob, coord, wcls,
                                                         partials, nb, out);
}

// Round 2
// 138.636 us; speedup vs baseline: 1.0570x; 1.0570x over previous
//
#include <hip/hip_runtime.h>
#include <cstdint>
#include <cstddef>

// Problem constants (from reference)
#define B_    2
#define A_    3
#define NCLS_ 3
#define CH_   9      // N_CLS * A
#define D_    64
#define H_    128
#define W_    128
#define M_    128
#define TD    16     // d-planes per block tile
#define EPS_      1e-4f
#define ONE_M_EPS 0.9999f
#define NLOG2E    -1.4426950408889634f   // -log2(e)
#define LN2_      0.6931471805599453f

__device__ __forceinline__ float4 fmax4(float4 a, float4 b) {
    return make_float4(fmaxf(a.x, b.x), fmaxf(a.y, b.y),
                       fmaxf(a.z, b.z), fmaxf(a.w, b.w));
}

// gfx950: __builtin_amdgcn_exp2f = v_exp_f32 (2^x), __builtin_amdgcn_logf =
// v_log_f32 (log2 x) — per __clang_hip_math.h.
__device__ __forceinline__ float exp2_fast(float x) { return __builtin_amdgcn_exp2f(x); }
__device__ __forceinline__ float log2_fast(float x) { return __builtin_amdgcn_logf(x); }

// ---------------------------------------------------------------------------
// Negative-term kernel — d-loop register ring (R11).
// R10 post-mortem: LDS d-sharing regressed 40->64.5 us. Counters: VALUBusy
// 12.6%, HBM 10.8% => latency/issue-bound; the per-iter __syncthreads emits
// s_waitcnt vmcnt(0) (compiler barrier semantics) and drained the whole
// prefetch pipeline every row. Fix: restructure so NO barriers and NO LDS are
// needed. Loop over d; 3x3x3 max is separable:
//   hwm[d](h,w) = max over h-1..h+1 of plane d   (vertical, per plane)
//   out[d]      = w-max of max(hwm[d-1], hwm[d], hwm[d+1])
// hwm ring lives in registers => each logits plane is loaded ONCE (center) —
// the d+-1 redundancy of R9 (3 plane loads/iter) is gone.
// h-neighbors: wave w covers rows 2w (half A, lanes 0-31) and 2w+1 (half B);
// the row between halves moves by __shfl(lane^32) (intra-wave, no barrier);
// the outer halo row (r-1 for half A, r+1 for half B) is one extra load.
// Loads: 3 float4/lane/iter (center + halo + pg) vs R9's 4, with 2-plane-deep
// prefetch (~2 iters latency cover) and ~18 waves/CU on top.
// Borders: d/h replicate-clamp (identity under max), w via -inf select.
// Exact float max => (pooled == logits) matches the reference bit-exact.
// Swizzle: 1152 = 8 XCD x 144 chunk (bijective); within a chunk htile is
// fastest then dchunk then bc.
// ---------------------------------------------------------------------------
struct Raw { float4 c, e, pg; };

__global__ __launch_bounds__(256) void neg_kernel(
    const float* __restrict__ logits, const float* __restrict__ prob,
    float* __restrict__ partials)
{
    const int orig = blockIdx.x;
    const int swz  = (orig & 7) * 144 + (orig >> 3);   // chunked XCD swizzle
    const int tid  = threadIdx.x;
    const int lw   = tid & 31;            // w-segment index
    const int lane = tid & 63;
    const int hwi  = tid >> 5;            // 0..7: row within tile
    const int half = hwi & 1;             // 0 = lower row of wave, 1 = upper
    const float NEG = -INFINITY;

    // tile decode: htile fastest, then dchunk, then bc
    const int htile  = swz & 15;          // 0..15 -> 8 h-rows each
    const int dchunk = (swz >> 4) & 3;    // 0..3  -> 16 d-planes each
    const int bc     = swz >> 6;          // 0..17 channel index b*CH + c
    const int b = bc / CH_;
    const int a = (bc - b * CH_) % A_;    // negmask channel -> a = c % A
    const int d0 = dchunk * TD;
    const int r  = htile * 8 + hwi;       // this thread's h-row (fixed)
    const int er = half ? min(r + 1, H_ - 1) : max(r - 1, 0);  // halo row

    const size_t HW = (size_t)H_ * W_;
    const float* Cb = logits + (size_t)bc * D_ * HW + (size_t)r  * W_ + 4 * lw;
    const float* Eb = logits + (size_t)bc * D_ * HW + (size_t)er * W_ + 4 * lw;
    const float* Pb = prob + (size_t)(b * A_ + a) * D_ * HW + (size_t)r * W_ + 4 * lw;

    auto ldc = [&](int dq) -> float4 {
        const int dc = min(max(dq, 0), D_ - 1);   // d replicate-clamp
        return *(const float4*)(Cb + (size_t)dc * HW);
    };
    auto lde = [&](int dq) -> float4 {
        const int dc = min(max(dq, 0), D_ - 1);
        return *(const float4*)(Eb + (size_t)dc * HW);
    };
    auto ldpg = [&](int dq) -> float4 {
        const int dc = min(max(dq, 0), D_ - 1);
        return *(const float4*)(Pb + (size_t)dc * HW);
    };
    // partner row (other half of the wave, same w segment)
    auto shfl4 = [&](float4 v) -> float4 {
        const int p = lane ^ 32;
        return make_float4(__shfl(v.x, p, 64), __shfl(v.y, p, 64),
                           __shfl(v.z, p, 64), __shfl(v.w, p, 64));
    };
    // vertical (h-direction) 3-row max of one plane
    auto hv = [&](const Raw& rw) -> float4 {
        return fmax4(rw.c, fmax4(rw.e, shfl4(rw.c)));
    };

    // ---- prologue: planes d0-1 .. d0+2 in flight ----
    Raw rm1; rm1.c = ldc(d0 - 1); rm1.e = lde(d0 - 1);
    Raw r0;  r0.c  = ldc(d0);     r0.e  = lde(d0);     r0.pg  = ldpg(d0);
    Raw rawD; rawD.c = ldc(d0+1); rawD.e = lde(d0+1);  rawD.pg = ldpg(d0+1);
    Raw rawE; rawE.c = ldc(d0+2); rawE.e = lde(d0+2);  rawE.pg = ldpg(d0+2);

    float4 hwmA = hv(rm1);       // hwm[d0-1]
    float4 hwmB = hv(r0);        // hwm[d0]
    float4 xc   = r0.c;          // center values of output plane d0
    float4 pgc  = r0.pg;

    float lacc2 = 0.0f, cacc = 0.0f;   // lacc2 accumulates log2 units

    #pragma unroll
    for (int j = 0; j < TD; ++j) {
        // issue plane d0+j+3 (deepest) before touching anything in flight
        Raw rawN = rawE;
        if (j <= TD - 3) {
            rawN.c = ldc(d0 + j + 3); rawN.e = lde(d0 + j + 3);
            rawN.pg = ldpg(d0 + j + 3);
        }

        // combine plane d+1 (issued 2 iterations ago)
        const float4 hwmC = hv(rawD);      // hwm[d+1]
        const float4 xN   = rawD.c;
        const float4 pgN  = rawD.pg;

        // d-direction max for output plane d = d0+j
        float4 cm = fmax4(hwmA, fmax4(hwmB, hwmC));
        // w-direction neighbors across lanes (w borders: -inf select)
        const float lftv = __shfl(cm.w, (lane + 63) & 63, 64);
        const float rgtv = __shfl(cm.x, (lane + 1) & 63, 64);
        const float left  = (lw == 0)  ? NEG : lftv;
        const float right = (lw == 31) ? NEG : rgtv;
        float4 m;
        m.x = fmaxf(left, fmaxf(cm.x, cm.y));
        m.y = fmaxf(cm.x, fmaxf(cm.y, cm.z));
        m.z = fmaxf(cm.y, fmaxf(cm.z, cm.w));
        m.w = fmaxf(cm.z, fmaxf(cm.w, right));

        // epilogue: cheap pre-condition; wave-uniform skip of transcendentals
        {
            const float x = xc.x;
            const bool pre = (pgc.x == -1.0f) & (m.x == x);
            if (__any(pre)) {
                const float u = exp2_fast(x * NLOG2E);             // e^-x
                const float p = __builtin_amdgcn_fmed3f(
                                    __builtin_amdgcn_rcpf(1.0f + u), EPS_, ONE_M_EPS);
                const float wn = (pre & (p > EPS_)) ? p * p : 0.0f;
                cacc += wn;
                lacc2 = fmaf(log2_fast(1.0f - p), wn, lacc2);
            }
        }
        {
            const float x = xc.y;
            const bool pre = (pgc.y == -1.0f) & (m.y == x);
            if (__any(pre)) {
                const float u = exp2_fast(x * NLOG2E);
                const float p = __builtin_amdgcn_fmed3f(
                                    __builtin_amdgcn_rcpf(1.0f + u), EPS_, ONE_M_EPS);
                const float wn = (pre & (p > EPS_)) ? p * p : 0.0f;
                cacc += wn;
                lacc2 = fmaf(log2_fast(1.0f - p), wn, lacc2);
            }
        }
        {
            const float x = xc.z;
            const bool pre = (pgc.z == -1.0f) & (m.z == x);
            if (__any(pre)) {
                const float u = exp2_fast(x * NLOG2E);
                const float p = __builtin_amdgcn_fmed3f(
                                    __builtin_amdgcn_rcpf(1.0f + u), EPS_, ONE_M_EPS);
                const float wn = (pre & (p > EPS_)) ? p * p : 0.0f;
                cacc += wn;
                lacc2 = fmaf(log2_fast(1.0f - p), wn, lacc2);
            }
        }
        {
            const float x = xc.w;
            const bool pre = (pgc.w == -1.0f) & (m.w == x);
            if (__any(pre)) {
                const float u = exp2_fast(x * NLOG2E);
                const float p = __builtin_amdgcn_fmed3f(
                                    __builtin_amdgcn_rcpf(1.0f + u), EPS_, ONE_M_EPS);
                const float wn = (pre & (p > EPS_)) ? p * p : 0.0f;
                cacc += wn;
                lacc2 = fmaf(log2_fast(1.0f - p), wn, lacc2);
            }
        }

        // rotate rings
        hwmA = hwmB; hwmB = hwmC;
        xc = xN; pgc = pgN;
        rawD = rawE; rawE = rawN;
    }

    float lacc = lacc2 * (-LN2_);      // convert log2 -> -ln

    // block reduction: wave shuffle then cross-wave via LDS
    #pragma unroll
    for (int off = 32; off > 0; off >>= 1) {
        lacc += __shfl_down(lacc, off);
        cacc += __shfl_down(cacc, off);
    }
    __shared__ float rl[4], rc[4];
    const int wv = threadIdx.x >> 6;
    if (lane == 0) { rl[wv] = lacc; rc[wv] = cacc; }
    __syncthreads();
    if (threadIdx.x == 0) {
        partials[2 * (size_t)blockIdx.x]     = rl[0] + rl[1] + rl[2] + rl[3];
        partials[2 * (size_t)blockIdx.x + 1] = rc[0] + rc[1] + rc[2] + rc[3];
    }
}

// ---------------------------------------------------------------------------
// Fused positive/other terms + final reduction (single block).
// Output order: [sum l_pos, loss_neg, sum l_oth, sum c_pos, count_neg, sum c_oth]
// ---------------------------------------------------------------------------
__global__ __launch_bounds__(256) void pos_reduce_kernel(
    const float* __restrict__ logits, const float* __restrict__ prob,
    const int* __restrict__ coord, const float* __restrict__ wcls,
    const float* __restrict__ partials, int nb, float* __restrict__ out)
{
    const int tid = threadIdx.x;
    const int b = tid >> 7;               // 0 or 1
    const int m = tid & (M_ - 1);
    __shared__ int zr[B_][NCLS_];
    if (tid < B_ * NCLS_) zr[tid / NCLS_][tid % NCLS_] = 0;
    __syncthreads();

    const int* cg = coord + ((size_t)b * M_ + m) * 4;
    const int c0 = cg[0];
    const bool valid = c0 > -1;
    const int a = valid ? c0    : 0;
    const int d = valid ? cg[1] : 0;
    const int h = valid ? cg[2] : 0;
    const int w = valid ? cg[3] : 0;

    const size_t HW = (size_t)H_ * W_;
    const size_t sp = (size_t)d * HW + (size_t)h * W_ + w;

    const float pv = prob[((size_t)b * A_ + a) * D_ * HW + sp];
    const int cls = valid ? ((int)pv - 1) : 0;
    if (valid) zr[b][cls] = 1;            // zero_rows flags (benign race)
    __syncthreads();

    auto sigclip = [](float x) {
        float p = 1.0f / (1.0f + __expf(-x));
        return fminf(fmaxf(p, EPS_), ONE_M_EPS);
    };

    const float vf = valid ? 1.0f : 0.0f;
    const float pt = sigclip(logits[((size_t)(b * CH_ + cls * A_ + a)) * D_ * HW + sp]);
    const float wp = (1.0f - pt) * (1.0f - pt) * wcls[cls] * vf;
    float lpos = -__logf(pt) * wp;
    float cpos = wp;

    float loth = 0.0f, coth = 0.0f;
    const bool ptg = pt > 0.5f;
    #pragma unroll
    for (int cc = 0; cc < NCLS_; ++cc) {
        const float po = sigclip(logits[((size_t)(b * CH_ + cc * A_ + a)) * D_ * HW + sp]);
        float wo = fmaxf(po - (pt - 0.1f), 0.0f);
        wo = (po > 0.5f && ptg) ? wo : 0.0f;
        wo = zr[b][cc] ? 0.0f : wo;
        wo *= vf;
        loth -= __logf(1.0f - po) * wo;
        coth += wo;
    }

    // neg partials (grid is 1 block; stride over nb)
    float l = 0.0f, c = 0.0f;
    for (int i = tid; i < nb; i += 256) {
        l += partials[2 * (size_t)i];
        c += partials[2 * (size_t)i + 1];
    }

    #pragma unroll
    for (int off = 32; off > 0; off >>= 1) {
        lpos += __shfl_down(lpos, off);
        cpos += __shfl_down(cpos, off);
        loth += __shfl_down(loth, off);
        coth += __shfl_down(coth, off);
        l    += __shfl_down(l, off);
        c    += __shfl_down(c, off);
    }
    __shared__ float r6[4][6];
    const int lane = tid & 63, wv = tid >> 6;
    if (lane == 0) {
        r6[wv][0] = lpos; r6[wv][1] = cpos; r6[wv][2] = loth;
        r6[wv][3] = coth; r6[wv][4] = l;    r6[wv][5] = c;
    }
    __syncthreads();
    if (tid == 0) {
        out[0] = r6[0][0] + r6[1][0] + r6[2][0] + r6[3][0];  // sum l_pos
        out[3] = r6[0][1] + r6[1][1] + r6[2][1] + r6[3][1];  // sum c_pos
        out[2] = r6[0][2] + r6[1][2] + r6[2][2] + r6[3][2];  // sum l_oth
        out[5] = r6[0][3] + r6[1][3] + r6[2][3] + r6[3][3];  // sum c_oth
        out[1] = r6[0][4] + r6[1][4] + r6[2][4] + r6[3][4];  // loss_neg
        out[4] = r6[0][5] + r6[1][5] + r6[2][5] + r6[3][5];  // count_neg
    }
}

extern "C" void kernel_launch(void* const* d_in, const int* in_sizes, int n_in,
                              void* d_out, int out_size, void* d_ws, size_t ws_size,
                              hipStream_t stream)
{
    const float* logits = (const float*)d_in[0];
    const float* prob   = (const float*)d_in[1];
    const int*   coord  = (const int*)d_in[2];
    const float* wcls   = (const float*)d_in[3];
    float* out = (float*)d_out;

    const int nb = B_ * CH_ * (H_ / 8) * (D_ / TD);    // 1152 blocks, exact

    float* partials = (float*)d_ws;          // nb * 2 floats

    neg_kernel<<<dim3(nb), dim3(256), 0, stream>>>(logits, prob, partials);
    pos_reduce_kernel<<<dim3(1), dim3(256), 0, stream>>>(logits, prob, coord, wcls,
                                                         partials, nb, out);
}